// Round 1
// baseline (20.408 us; speedup 1.0000x reference)
//
#include <hip/hip_runtime.h>
#include <math.h>

// QuanConv2D collapsed form:
//   d_k = alpha_k*cos(pi*x_k) + beta_k*sin(pi*x_k)   (per patch element k=0..3)
//   out0 = d1*d2*d3, out1 = d0*d1, out2 = d0*d1*d2, out3 = d0*d1*d2*d3
// alpha/beta derived from weight once per launch (8 floats in d_ws).

#define W_MUL 0.632455532033675866f  // sqrt(2/5)

struct cplx { float x, y; };
__device__ inline cplx cmul(cplx a, cplx b) { return {a.x*b.x - a.y*b.y, a.x*b.y + a.y*b.x}; }
__device__ inline cplx cadd(cplx a, cplx b) { return {a.x + b.x, a.y + b.y}; }
__device__ inline float cabs2(cplx a) { return a.x*a.x + a.y*a.y; }

__global__ void precompute_coeffs(const float* __restrict__ w, float* __restrict__ coeff) {
    int k = threadIdx.x;
    if (k >= 4) return;
    float t0 = w[3*k+0] * W_MUL;
    float t1 = w[3*k+1] * W_MUL;
    float t2 = w[3*k+2] * W_MUL;
    float c0 = cosf(0.5f*t0), s0 = sinf(0.5f*t0);
    float c1 = cosf(0.5f*t1), s1 = sinf(0.5f*t1);
    float c2v = cosf(0.5f*t2), s2 = sinf(0.5f*t2);
    // Rx(t) = [[c, -i s], [-i s, c]];  Rz(t) = [[e^{-it/2}, 0], [0, e^{+it/2}]]
    cplx Rx0[2][2] = {{{c0, 0.f}, {0.f, -s0}}, {{0.f, -s0}, {c0, 0.f}}};
    cplx Rz1[2][2] = {{{c1, -s1}, {0.f, 0.f}}, {{0.f, 0.f}, {c1, s1}}};
    cplx Rx2[2][2] = {{{c2v, 0.f}, {0.f, -s2}}, {{0.f, -s2}, {c2v, 0.f}}};
    cplx M[2][2], G[2][2];
    for (int i = 0; i < 2; ++i)
        for (int j = 0; j < 2; ++j) {
            cplx acc = {0.f, 0.f};
            for (int l = 0; l < 2; ++l) acc = cadd(acc, cmul(Rz1[i][l], Rx0[l][j]));
            M[i][j] = acc;
        }
    for (int i = 0; i < 2; ++i)
        for (int j = 0; j < 2; ++j) {
            cplx acc = {0.f, 0.f};
            for (int l = 0; l < 2; ++l) acc = cadd(acc, cmul(Rx2[i][l], M[l][j]));
            G[i][j] = acc;
        }
    // alpha = d at x=0 (a=(1,0));  beta = d at x=1/2 (a=(r,r), r=sqrt(1/2))
    float alpha = cabs2(G[0][0]) - cabs2(G[1][0]);
    cplx u0 = cadd(G[0][0], G[0][1]);
    cplx u1 = cadd(G[1][0], G[1][1]);
    float beta = 0.5f * (cabs2(u0) - cabs2(u1));
    coeff[k] = alpha;
    coeff[4 + k] = beta;
}

__device__ inline float dval(float x, float A, float B) {
    float s, c;
    __sincosf(3.14159265358979323846f * x, &s, &c);
    return fmaf(A, c, B * s);
}

// B=32, H=W=512, Ho=Wo=256. One thread handles 2 horizontal patches
// (4 input cols x 2 rows -> 2 output cols in each of 4 planes).
__global__ __launch_bounds__(256) void quanconv_main(const float* __restrict__ in,
                                                     const float* __restrict__ coeff,
                                                     float* __restrict__ out) {
    const int tid = blockIdx.x * 256 + threadIdx.x;   // 0 .. 32*256*128-1
    const int j2 = tid & 127;          // horizontal pair index (2 patches)
    const int i  = (tid >> 7) & 255;   // output row
    const int b  = tid >> 15;          // batch

    const float A0 = coeff[0], A1 = coeff[1], A2 = coeff[2], A3 = coeff[3];
    const float B0 = coeff[4], B1 = coeff[5], B2 = coeff[6], B3 = coeff[7];

    const float* p = in + ((size_t)b << 18) + ((size_t)i << 10) + (j2 << 2);
    const float4 r0 = *(const float4*)p;          // row 2i, cols 4j2..4j2+3
    const float4 r1 = *(const float4*)(p + 512);  // row 2i+1

    // patch A: x0=r0.x x1=r0.y x2=r1.x x3=r1.y ; patch B: r0.z r0.w r1.z r1.w
    const float dA0 = dval(r0.x, A0, B0);
    const float dA1 = dval(r0.y, A1, B1);
    const float dA2 = dval(r1.x, A2, B2);
    const float dA3 = dval(r1.y, A3, B3);
    const float dB0 = dval(r0.z, A0, B0);
    const float dB1 = dval(r0.w, A1, B1);
    const float dB2 = dval(r1.z, A2, B2);
    const float dB3 = dval(r1.w, A3, B3);

    const float eA1 = dA0 * dA1;
    const float eA2 = eA1 * dA2;
    const float eA3 = eA2 * dA3;
    const float eA0 = dA1 * dA2 * dA3;
    const float eB1 = dB0 * dB1;
    const float eB2 = eB1 * dB2;
    const float eB3 = eB2 * dB3;
    const float eB0 = dB1 * dB2 * dB3;

    float* o = out + ((size_t)b << 18) + ((size_t)i << 8) + (j2 << 1);
    *(float2*)(o)               = {eA0, eB0};
    *(float2*)(o + (1 << 16))   = {eA1, eB1};
    *(float2*)(o + (2 << 16))   = {eA2, eB2};
    *(float2*)(o + (3 << 16))   = {eA3, eB3};
}

extern "C" void kernel_launch(void* const* d_in, const int* in_sizes, int n_in,
                              void* d_out, int out_size, void* d_ws, size_t ws_size,
                              hipStream_t stream) {
    const float* input  = (const float*)d_in[0];
    const float* weight = (const float*)d_in[1];
    float* out   = (float*)d_out;
    float* coeff = (float*)d_ws;

    precompute_coeffs<<<1, 64, 0, stream>>>(weight, coeff);
    quanconv_main<<<4096, 256, 0, stream>>>(input, coeff, out);
}

// Round 2
// 16.400 us; speedup vs baseline: 1.2444x; 1.2444x over previous
//
#include <hip/hip_runtime.h>
#include <math.h>

// QuanConv2D collapsed form:
//   d_k = alpha_k*cos(pi*x_k) + beta_k*sin(pi*x_k)   (per patch element k=0..3)
//   out0 = d1*d2*d3, out1 = d0*d1, out2 = d0*d1*d2, out3 = d0*d1*d2*d3
// alpha/beta computed per-block from weight into LDS (fused, single dispatch).

#define W_MUL 0.632455532033675866f  // sqrt(2/5)

struct cplx { float x, y; };
__device__ inline cplx cmul(cplx a, cplx b) { return {a.x*b.x - a.y*b.y, a.x*b.y + a.y*b.x}; }
__device__ inline cplx cadd(cplx a, cplx b) { return {a.x + b.x, a.y + b.y}; }
__device__ inline float cabs2(cplx a) { return a.x*a.x + a.y*a.y; }

__device__ inline float dval(float x, float A, float B) {
    float s, c;
    __sincosf(3.14159265358979323846f * x, &s, &c);
    return fmaf(A, c, B * s);
}

// B=32, H=W=512, Ho=Wo=256. One thread handles 4 horizontal patches
// (8 input cols x 2 rows -> 4 output cols in each of 4 planes).
// 32*256*64 = 524288 threads = 2048 blocks of 256.
__global__ __launch_bounds__(256) void quanconv_fused(const float* __restrict__ in,
                                                      const float* __restrict__ w,
                                                      float* __restrict__ out) {
    __shared__ float sc[8];
    if (threadIdx.x < 4) {
        const int k = threadIdx.x;
        float t0 = w[3*k+0] * W_MUL;
        float t1 = w[3*k+1] * W_MUL;
        float t2 = w[3*k+2] * W_MUL;
        float c0 = cosf(0.5f*t0), s0 = sinf(0.5f*t0);
        float c1 = cosf(0.5f*t1), s1 = sinf(0.5f*t1);
        float c2v = cosf(0.5f*t2), s2 = sinf(0.5f*t2);
        // Rx(t) = [[c, -i s], [-i s, c]];  Rz(t) = [[e^{-it/2}, 0], [0, e^{+it/2}]]
        cplx Rx0[2][2] = {{{c0, 0.f}, {0.f, -s0}}, {{0.f, -s0}, {c0, 0.f}}};
        cplx Rz1[2][2] = {{{c1, -s1}, {0.f, 0.f}}, {{0.f, 0.f}, {c1, s1}}};
        cplx Rx2[2][2] = {{{c2v, 0.f}, {0.f, -s2}}, {{0.f, -s2}, {c2v, 0.f}}};
        cplx M[2][2], G[2][2];
        for (int i = 0; i < 2; ++i)
            for (int j = 0; j < 2; ++j) {
                cplx acc = {0.f, 0.f};
                for (int l = 0; l < 2; ++l) acc = cadd(acc, cmul(Rz1[i][l], Rx0[l][j]));
                M[i][j] = acc;
            }
        for (int i = 0; i < 2; ++i)
            for (int j = 0; j < 2; ++j) {
                cplx acc = {0.f, 0.f};
                for (int l = 0; l < 2; ++l) acc = cadd(acc, cmul(Rx2[i][l], M[l][j]));
                G[i][j] = acc;
            }
        // alpha = d at x=0 (a=(1,0));  beta = d at x=1/2 (a=(r,r), r=sqrt(1/2))
        sc[k]     = cabs2(G[0][0]) - cabs2(G[1][0]);
        cplx u0 = cadd(G[0][0], G[0][1]);
        cplx u1 = cadd(G[1][0], G[1][1]);
        sc[4 + k] = 0.5f * (cabs2(u0) - cabs2(u1));
    }
    __syncthreads();

    const int tid = blockIdx.x * 256 + threadIdx.x;
    const int j4 = tid & 63;           // group of 4 horizontal patches
    const int i  = (tid >> 6) & 255;   // output row
    const int b  = tid >> 14;          // batch

    const float A0 = sc[0], A1 = sc[1], A2 = sc[2], A3 = sc[3];
    const float B0 = sc[4], B1 = sc[5], B2 = sc[6], B3 = sc[7];

    const float* p = in + ((size_t)b << 18) + ((size_t)i << 10) + (j4 << 3);
    const float4 r0a = *(const float4*)p;          // row 2i,   cols 8j..8j+3
    const float4 r0b = *(const float4*)(p + 4);    // row 2i,   cols 8j+4..8j+7
    const float4 r1a = *(const float4*)(p + 512);  // row 2i+1, cols 8j..8j+3
    const float4 r1b = *(const float4*)(p + 516);  // row 2i+1, cols 8j+4..8j+7

    // patch q: top = (x0,x1), bottom = (x2,x3)
    float d0[4], d1[4], d2[4], d3[4];
    d0[0] = dval(r0a.x, A0, B0); d1[0] = dval(r0a.y, A1, B1);
    d2[0] = dval(r1a.x, A2, B2); d3[0] = dval(r1a.y, A3, B3);
    d0[1] = dval(r0a.z, A0, B0); d1[1] = dval(r0a.w, A1, B1);
    d2[1] = dval(r1a.z, A2, B2); d3[1] = dval(r1a.w, A3, B3);
    d0[2] = dval(r0b.x, A0, B0); d1[2] = dval(r0b.y, A1, B1);
    d2[2] = dval(r1b.x, A2, B2); d3[2] = dval(r1b.y, A3, B3);
    d0[3] = dval(r0b.z, A0, B0); d1[3] = dval(r0b.w, A1, B1);
    d2[3] = dval(r1b.z, A2, B2); d3[3] = dval(r1b.w, A3, B3);

    float4 o0, o1, o2, o3;
    float* e1 = &o1.x; float* e2 = &o2.x; float* e3 = &o3.x; float* e0 = &o0.x;
    #pragma unroll
    for (int q = 0; q < 4; ++q) {
        const float p01 = d0[q] * d1[q];
        const float p012 = p01 * d2[q];
        e1[q] = p01;
        e2[q] = p012;
        e3[q] = p012 * d3[q];
        e0[q] = d1[q] * d2[q] * d3[q];
    }

    float* o = out + ((size_t)b << 18) + ((size_t)i << 8) + (j4 << 2);
    *(float4*)(o)             = o0;
    *(float4*)(o + (1 << 16)) = o1;
    *(float4*)(o + (2 << 16)) = o2;
    *(float4*)(o + (3 << 16)) = o3;
}

extern "C" void kernel_launch(void* const* d_in, const int* in_sizes, int n_in,
                              void* d_out, int out_size, void* d_ws, size_t ws_size,
                              hipStream_t stream) {
    const float* input  = (const float*)d_in[0];
    const float* weight = (const float*)d_in[1];
    float* out = (float*)d_out;
    quanconv_fused<<<2048, 256, 0, stream>>>(input, weight, out);
}

// Round 3
// 16.184 us; speedup vs baseline: 1.2610x; 1.0133x over previous
//
#include <hip/hip_runtime.h>
#include <math.h>

// QuanConv2D collapsed form:
//   d_k = alpha_k*cos(pi*x_k) + beta_k*sin(pi*x_k)   (per patch element k=0..3)
//   out0 = d1*d2*d3, out1 = d0*d1, out2 = d0*d1*d2, out3 = d0*d1*d2*d3
// alpha/beta computed per-block from weight into LDS (fused, single dispatch).
// sin(pi*x)/cos(pi*x) via raw v_sin_f32/v_cos_f32 (input in revolutions: 0.5*x).

#define W_MUL 0.632455532033675866f  // sqrt(2/5)

struct cplx { float x, y; };
__device__ inline cplx cmul(cplx a, cplx b) { return {a.x*b.x - a.y*b.y, a.x*b.y + a.y*b.x}; }
__device__ inline cplx cadd(cplx a, cplx b) { return {a.x + b.x, a.y + b.y}; }
__device__ inline float cabs2(cplx a) { return a.x*a.x + a.y*a.y; }

__device__ inline float dval(float x, float A, float B) {
    // sin(pi*x) = v_sin(x/2 rev), cos(pi*x) = v_cos(x/2 rev)
    const float h = 0.5f * x;
    const float s = __builtin_amdgcn_sinf(h);
    const float c = __builtin_amdgcn_cosf(h);
    return fmaf(A, c, B * s);
}

// B=32, H=W=512, Ho=Wo=256. One thread handles 4 horizontal patches
// (8 input cols x 2 rows -> 4 output cols in each of 4 planes).
// 32*256*64 = 524288 threads = 2048 blocks of 256 -> 8 blocks/CU, 32 waves/CU.
__global__ __launch_bounds__(256, 8) void quanconv_fused(const float* __restrict__ in,
                                                         const float* __restrict__ w,
                                                         float* __restrict__ out) {
    __shared__ float sc[8];

    // Issue global loads FIRST so VMEM latency overlaps coeff compute + sync.
    const int tid = blockIdx.x * 256 + threadIdx.x;
    const int j4 = tid & 63;           // group of 4 horizontal patches
    const int i  = (tid >> 6) & 255;   // output row
    const int b  = tid >> 14;          // batch

    const float* p = in + ((size_t)b << 18) + ((size_t)i << 10) + (j4 << 3);
    const float4 r0a = *(const float4*)p;          // row 2i,   cols 8j..8j+3
    const float4 r0b = *(const float4*)(p + 4);    // row 2i,   cols 8j+4..8j+7
    const float4 r1a = *(const float4*)(p + 512);  // row 2i+1, cols 8j..8j+3
    const float4 r1b = *(const float4*)(p + 516);  // row 2i+1, cols 8j+4..8j+7

    if (threadIdx.x < 4) {
        const int k = threadIdx.x;
        float t0 = w[3*k+0] * W_MUL;
        float t1 = w[3*k+1] * W_MUL;
        float t2 = w[3*k+2] * W_MUL;
        float c0 = cosf(0.5f*t0), s0 = sinf(0.5f*t0);
        float c1 = cosf(0.5f*t1), s1 = sinf(0.5f*t1);
        float c2v = cosf(0.5f*t2), s2 = sinf(0.5f*t2);
        // Rx(t) = [[c, -i s], [-i s, c]];  Rz(t) = [[e^{-it/2}, 0], [0, e^{+it/2}]]
        cplx Rx0[2][2] = {{{c0, 0.f}, {0.f, -s0}}, {{0.f, -s0}, {c0, 0.f}}};
        cplx Rz1[2][2] = {{{c1, -s1}, {0.f, 0.f}}, {{0.f, 0.f}, {c1, s1}}};
        cplx Rx2[2][2] = {{{c2v, 0.f}, {0.f, -s2}}, {{0.f, -s2}, {c2v, 0.f}}};
        cplx M[2][2], G[2][2];
        for (int ii = 0; ii < 2; ++ii)
            for (int jj = 0; jj < 2; ++jj) {
                cplx acc = {0.f, 0.f};
                for (int l = 0; l < 2; ++l) acc = cadd(acc, cmul(Rz1[ii][l], Rx0[l][jj]));
                M[ii][jj] = acc;
            }
        for (int ii = 0; ii < 2; ++ii)
            for (int jj = 0; jj < 2; ++jj) {
                cplx acc = {0.f, 0.f};
                for (int l = 0; l < 2; ++l) acc = cadd(acc, cmul(Rx2[ii][l], M[l][jj]));
                G[ii][jj] = acc;
            }
        // alpha = d at x=0 (a=(1,0));  beta = d at x=1/2 (a=(r,r), r=sqrt(1/2))
        sc[k]     = cabs2(G[0][0]) - cabs2(G[1][0]);
        cplx u0 = cadd(G[0][0], G[0][1]);
        cplx u1 = cadd(G[1][0], G[1][1]);
        sc[4 + k] = 0.5f * (cabs2(u0) - cabs2(u1));
    }
    __syncthreads();

    const float A0 = sc[0], A1 = sc[1], A2 = sc[2], A3 = sc[3];
    const float B0 = sc[4], B1 = sc[5], B2 = sc[6], B3 = sc[7];

    // patch q: top = (x0,x1), bottom = (x2,x3)
    float d0[4], d1[4], d2[4], d3[4];
    d0[0] = dval(r0a.x, A0, B0); d1[0] = dval(r0a.y, A1, B1);
    d2[0] = dval(r1a.x, A2, B2); d3[0] = dval(r1a.y, A3, B3);
    d0[1] = dval(r0a.z, A0, B0); d1[1] = dval(r0a.w, A1, B1);
    d2[1] = dval(r1a.z, A2, B2); d3[1] = dval(r1a.w, A3, B3);
    d0[2] = dval(r0b.x, A0, B0); d1[2] = dval(r0b.y, A1, B1);
    d2[2] = dval(r1b.x, A2, B2); d3[2] = dval(r1b.y, A3, B3);
    d0[3] = dval(r0b.z, A0, B0); d1[3] = dval(r0b.w, A1, B1);
    d2[3] = dval(r1b.z, A2, B2); d3[3] = dval(r1b.w, A3, B3);

    float4 o0, o1, o2, o3;
    float* e0 = &o0.x; float* e1 = &o1.x; float* e2 = &o2.x; float* e3 = &o3.x;
    #pragma unroll
    for (int q = 0; q < 4; ++q) {
        const float p01 = d0[q] * d1[q];
        const float p012 = p01 * d2[q];
        e1[q] = p01;
        e2[q] = p012;
        e3[q] = p012 * d3[q];
        e0[q] = d1[q] * d2[q] * d3[q];
    }

    float* o = out + ((size_t)b << 18) + ((size_t)i << 8) + (j4 << 2);
    *(float4*)(o)             = o0;
    *(float4*)(o + (1 << 16)) = o1;
    *(float4*)(o + (2 << 16)) = o2;
    *(float4*)(o + (3 << 16)) = o3;
}

extern "C" void kernel_launch(void* const* d_in, const int* in_sizes, int n_in,
                              void* d_out, int out_size, void* d_ws, size_t ws_size,
                              hipStream_t stream) {
    const float* input  = (const float*)d_in[0];
    const float* weight = (const float*)d_in[1];
    float* out = (float*)d_out;
    quanconv_fused<<<2048, 256, 0, stream>>>(input, weight, out);
}